// Round 1
// baseline (274.180 us; speedup 1.0000x reference)
//
#include <hip/hip_runtime.h>
#include <cmath>

#define C_CLASSES 21
#define EPS 1e-12f
#define IGNORE_INDEX (-1)

// d_ws layout: [0..7] double sum, [8..11] unsigned int valid count
struct PclWs {
    double sum;
    unsigned int cnt;
    unsigned int pad;
};

__global__ __launch_bounds__(256) void pcl_reduce_kernel(
    const float* __restrict__ input,     // [N, 21]
    const float* __restrict__ weight,    // [N]
    const float* __restrict__ pc_input,  // [4096]
    const int*   __restrict__ target,    // [N]
    const int*   __restrict__ cluster,   // [N]
    PclWs* __restrict__ ws,
    int n)
{
    const int tid  = blockIdx.x * blockDim.x + threadIdx.x;
    const int base = tid * 4;

    float lsum = 0.0f;
    int   lcnt = 0;

    if (base + 3 < n) {
        // Fully coalesced 16B vector loads for the three streamed arrays.
        const int4   t4 = *reinterpret_cast<const int4*>(target + base);
        const int4   c4 = *reinterpret_cast<const int4*>(cluster + base);
        const float4 w4 = *reinterpret_cast<const float4*>(weight + base);

        const int   ts[4] = {t4.x, t4.y, t4.z, t4.w};
        const int   cs[4] = {c4.x, c4.y, c4.z, c4.w};
        const float wv[4] = {w4.x, w4.y, w4.z, w4.w};

#pragma unroll
        for (int j = 0; j < 4; ++j) {
            const int t = ts[j];
            if (t == IGNORE_INDEX) continue;
            ++lcnt;
            float p;
            if (t == 0) {
                // background: own prob of class 0 — scattered, predicated load,
                // only ~1/21 of lanes take this path.
                p = input[(size_t)(base + j) * C_CLASSES];
            } else {
                // foreground: cluster-averaged prob — 16KB table, L1-resident.
                p = pc_input[cs[j]];
            }
            lsum += -wv[j] * logf(fmaxf(p, EPS));
        }
    } else if (base < n) {
        // tail (not hit for N=2^21, kept for generality)
        for (int j = 0; j < 4 && base + j < n; ++j) {
            const int i = base + j;
            const int t = target[i];
            if (t == IGNORE_INDEX) continue;
            ++lcnt;
            float p = (t == 0) ? input[(size_t)i * C_CLASSES]
                               : pc_input[cluster[i]];
            lsum += -weight[i] * logf(fmaxf(p, EPS));
        }
    }

    // wave64 shuffle reduction
#pragma unroll
    for (int off = 32; off > 0; off >>= 1) {
        lsum += __shfl_down(lsum, off, 64);
        lcnt += __shfl_down(lcnt, off, 64);
    }

    __shared__ float ssum[4];
    __shared__ int   scnt[4];
    const int wave = threadIdx.x >> 6;
    const int lane = threadIdx.x & 63;
    if (lane == 0) { ssum[wave] = lsum; scnt[wave] = lcnt; }
    __syncthreads();

    if (threadIdx.x == 0) {
        float bs = ssum[0] + ssum[1] + ssum[2] + ssum[3];
        int   bc = scnt[0] + scnt[1] + scnt[2] + scnt[3];
        atomicAdd(&ws->sum, (double)bs);
        atomicAdd(&ws->cnt, (unsigned int)bc);
    }
}

__global__ void pcl_finalize_kernel(const PclWs* __restrict__ ws,
                                    float* __restrict__ out)
{
    double denom = (double)ws->cnt;
    if (denom < 1.0) denom = 1.0;
    out[0] = (float)(ws->sum / denom);
}

extern "C" void kernel_launch(void* const* d_in, const int* in_sizes, int n_in,
                              void* d_out, int out_size, void* d_ws, size_t ws_size,
                              hipStream_t stream) {
    const float* input    = (const float*)d_in[0];
    const float* weight   = (const float*)d_in[1];
    const float* pc_input = (const float*)d_in[2];
    const int*   target   = (const int*)d_in[3];
    const int*   cluster  = (const int*)d_in[4];
    float* out = (float*)d_out;
    PclWs* ws  = (PclWs*)d_ws;

    const int n = in_sizes[1];  // weight has N elements

    // zero the accumulator (ws is re-poisoned to 0xAA before every launch)
    hipMemsetAsync(ws, 0, sizeof(PclWs), stream);

    const int threads = 256;
    const int groups  = (n + 3) / 4;
    const int blocks  = (groups + threads - 1) / threads;

    pcl_reduce_kernel<<<blocks, threads, 0, stream>>>(
        input, weight, pc_input, target, cluster, ws, n);

    pcl_finalize_kernel<<<1, 1, 0, stream>>>(ws, out);
}

// Round 2
// 230.580 us; speedup vs baseline: 1.1891x; 1.1891x over previous
//
#include <hip/hip_runtime.h>
#include <cmath>

#define C_CLASSES 21
#define EPS 1e-12f
#define IGNORE_INDEX (-1)
#define THREADS 256
#define EPT 8   // elements per thread

// d_ws layout: [0 .. nblocks) float partial sums, then [nblocks .. 2*nblocks) int partial counts.
// Every block writes its own slot -> no zero-init dispatch needed, no atomics.

__global__ __launch_bounds__(THREADS) void pcl_reduce_kernel(
    const float* __restrict__ input,     // [N, 21] — only column 0, only for t==0 rows
    const float* __restrict__ weight,    // [N]
    const float* __restrict__ pc_input,  // [4096] — L1-resident
    const int*   __restrict__ target,    // [N]
    const int*   __restrict__ cluster,   // [N]
    float* __restrict__ part_sum,        // [gridDim.x]
    int*   __restrict__ part_cnt,        // [gridDim.x]
    int n)
{
    const int tid  = blockIdx.x * THREADS + threadIdx.x;
    const int base = tid * EPT;

    float lsum = 0.0f;
    int   lcnt = 0;

    if (base + EPT - 1 < n) {
        // coalesced 16B vector loads, 2 each
        const int4   t0 = *reinterpret_cast<const int4*>(target + base);
        const int4   t1 = *reinterpret_cast<const int4*>(target + base + 4);
        const int4   c0 = *reinterpret_cast<const int4*>(cluster + base);
        const int4   c1 = *reinterpret_cast<const int4*>(cluster + base + 4);
        const float4 w0 = *reinterpret_cast<const float4*>(weight + base);
        const float4 w1 = *reinterpret_cast<const float4*>(weight + base + 4);

        const int   ts[EPT] = {t0.x, t0.y, t0.z, t0.w, t1.x, t1.y, t1.z, t1.w};
        const int   cs[EPT] = {c0.x, c0.y, c0.z, c0.w, c1.x, c1.y, c1.z, c1.w};
        const float wv[EPT] = {w0.x, w0.y, w0.z, w0.w, w1.x, w1.y, w1.z, w1.w};

#pragma unroll
        for (int j = 0; j < EPT; ++j) {
            const int t = ts[j];
            if (t == IGNORE_INDEX) continue;
            ++lcnt;
            float p;
            if (t == 0) {
                // background: scattered predicated load, ~1/21 of lanes
                p = input[(size_t)(base + j) * C_CLASSES];
            } else {
                // foreground: 16KB table gather, cache-resident
                p = pc_input[cs[j]];
            }
            lsum -= wv[j] * logf(fmaxf(p, EPS));
        }
    } else if (base < n) {
        for (int j = 0; j < EPT && base + j < n; ++j) {
            const int i = base + j;
            const int t = target[i];
            if (t == IGNORE_INDEX) continue;
            ++lcnt;
            float p = (t == 0) ? input[(size_t)i * C_CLASSES]
                               : pc_input[cluster[i]];
            lsum -= weight[i] * logf(fmaxf(p, EPS));
        }
    }

    // wave64 shuffle reduction
#pragma unroll
    for (int off = 32; off > 0; off >>= 1) {
        lsum += __shfl_down(lsum, off, 64);
        lcnt += __shfl_down(lcnt, off, 64);
    }

    __shared__ float ssum[THREADS / 64];
    __shared__ int   scnt[THREADS / 64];
    const int wave = threadIdx.x >> 6;
    const int lane = threadIdx.x & 63;
    if (lane == 0) { ssum[wave] = lsum; scnt[wave] = lcnt; }
    __syncthreads();

    if (threadIdx.x == 0) {
        float bs = 0.0f; int bc = 0;
#pragma unroll
        for (int w = 0; w < THREADS / 64; ++w) { bs += ssum[w]; bc += scnt[w]; }
        part_sum[blockIdx.x] = bs;
        part_cnt[blockIdx.x] = bc;
    }
}

__global__ __launch_bounds__(THREADS) void pcl_finalize_kernel(
    const float* __restrict__ part_sum,
    const int*   __restrict__ part_cnt,
    float* __restrict__ out,
    int nblocks)
{
    double lsum = 0.0;
    long long lcnt = 0;
    for (int i = threadIdx.x; i < nblocks; i += THREADS) {
        lsum += (double)part_sum[i];
        lcnt += part_cnt[i];
    }
#pragma unroll
    for (int off = 32; off > 0; off >>= 1) {
        lsum += __shfl_down(lsum, off, 64);
        lcnt += __shfl_down(lcnt, off, 64);
    }
    __shared__ double ssum[THREADS / 64];
    __shared__ long long scnt[THREADS / 64];
    const int wave = threadIdx.x >> 6;
    const int lane = threadIdx.x & 63;
    if (lane == 0) { ssum[wave] = lsum; scnt[wave] = lcnt; }
    __syncthreads();
    if (threadIdx.x == 0) {
        double s = 0.0; long long c = 0;
#pragma unroll
        for (int w = 0; w < THREADS / 64; ++w) { s += ssum[w]; c += scnt[w]; }
        double denom = (double)c;
        if (denom < 1.0) denom = 1.0;
        out[0] = (float)(s / denom);
    }
}

extern "C" void kernel_launch(void* const* d_in, const int* in_sizes, int n_in,
                              void* d_out, int out_size, void* d_ws, size_t ws_size,
                              hipStream_t stream) {
    const float* input    = (const float*)d_in[0];
    const float* weight   = (const float*)d_in[1];
    const float* pc_input = (const float*)d_in[2];
    const int*   target   = (const int*)d_in[3];
    const int*   cluster  = (const int*)d_in[4];
    float* out = (float*)d_out;

    const int n = in_sizes[1];  // weight has N elements

    const int groups = (n + EPT - 1) / EPT;
    const int blocks = (groups + THREADS - 1) / THREADS;  // 1024 for N=2^21

    float* part_sum = (float*)d_ws;
    int*   part_cnt = (int*)((char*)d_ws + (size_t)blocks * sizeof(float));

    pcl_reduce_kernel<<<blocks, THREADS, 0, stream>>>(
        input, weight, pc_input, target, cluster, part_sum, part_cnt, n);

    pcl_finalize_kernel<<<1, THREADS, 0, stream>>>(part_sum, part_cnt, out, blocks);
}